// Round 9
// baseline (733.150 us; speedup 1.0000x reference)
//
#include <hip/hip_runtime.h>
#include <math.h>

#define NN 50000
#define NE 600000
#define HID 128
#define NCLS 10
#define T2S 16  // padded row stride for the 10-class intermediate

typedef __bf16 bf16x8 __attribute__((ext_vector_type(8)));
typedef float f32x16 __attribute__((ext_vector_type(16)));

// Exact 3-way bf16 split: f == hi + mid + lo (bit-truncation splits are exact;
// fp32 has 24 mantissa bits, 3x bf16 planes carry 8+8+8 = all of them).
__device__ __forceinline__ void split3(float f, ushort& h, ushort& m, ushort& l) {
    unsigned uh = __float_as_uint(f) & 0xffff0000u;
    float fm = f - __uint_as_float(uh);
    unsigned um = __float_as_uint(fm) & 0xffff0000u;
    float fl = fm - __uint_as_float(um);
    h = (ushort)(uh >> 16);
    m = (ushort)(um >> 16);
    l = (ushort)(__float_as_uint(fl) >> 16);
}

// ================= graph prep: CSR by destination =================

__global__ __launch_bounds__(256) void k_count(const int* __restrict__ edge,
                                               int* __restrict__ counts) {
    int e = blockIdx.x * 256 + threadIdx.x;
    if (e < NE) atomicAdd(&counts[edge[NE + e]], 1);
}

__device__ __forceinline__ int wave_incl_scan(int x, int lane) {
#pragma unroll
    for (int off = 1; off < 64; off <<= 1) {
        int y = __shfl_up(x, off, 64);
        if (lane >= off) x += y;
    }
    return x;
}

__global__ __launch_bounds__(256) void k_scan1(const int* __restrict__ counts,
                                               int* __restrict__ rowptr,
                                               int* __restrict__ bsum,
                                               float* __restrict__ dinv) {
    __shared__ int ws[4];
    int tid = threadIdx.x;
    int i = blockIdx.x * 256 + tid;
    int lane = tid & 63, wv = tid >> 6;
    int v = (i < NN) ? counts[i] : 0;
    if (i < NN) dinv[i] = rsqrtf((float)(v + 1));
    int x = wave_incl_scan(v, lane);
    if (lane == 63) ws[wv] = x;
    __syncthreads();
    int off = 0;
    for (int j = 0; j < wv; ++j) off += ws[j];
    if (i < NN) rowptr[i] = off + x - v;
    if (tid == 255) bsum[blockIdx.x] = off + x;
}

__global__ __launch_bounds__(256) void k_scan2(int* __restrict__ bsum, int n) {
    __shared__ int ws[4];
    int tid = threadIdx.x;
    int lane = tid & 63, wv = tid >> 6;
    int v = (tid < n) ? bsum[tid] : 0;
    int x = wave_incl_scan(v, lane);
    if (lane == 63) ws[wv] = x;
    __syncthreads();
    int off = 0;
    for (int j = 0; j < wv; ++j) off += ws[j];
    __syncthreads();
    if (tid < n) bsum[tid] = off + x - v;
}

__global__ __launch_bounds__(256) void k_scan3(int* __restrict__ rowptr,
                                               const int* __restrict__ bsum) {
    int i = blockIdx.x * 256 + threadIdx.x;
    if (i < NN) rowptr[i] += bsum[blockIdx.x];
    if (i == 0) rowptr[NN] = NE;
}

// cursor == counts (still holds per-node counts after scan1); atomicSub gives
// slots count-1..0 -- order within a row is irrelevant for a sum.
__global__ __launch_bounds__(256) void k_fill(const int* __restrict__ edge,
                                              const int* __restrict__ rowptr,
                                              int* __restrict__ cursor,
                                              const float* __restrict__ dinv,
                                              int2* __restrict__ csr) {
    int e = blockIdx.x * 256 + threadIdx.x;
    if (e >= NE) return;
    int s = edge[e], d = edge[NE + e];
    int slot = atomicSub(&cursor[d], 1) - 1;
    csr[rowptr[d] + slot] = make_int2(s, __float_as_int(dinv[s] * dinv[d]));
}

// ================= one-time weight split =================
// W_stack [8][128 k][128 n] fp32 -> Wt4 [8][3 planes][8 ks][128 n][16] bf16.

__global__ __launch_bounds__(256) void k_split_w(const float* __restrict__ Wst,
                                                 ushort* __restrict__ Wt4) {
    int i = blockIdx.x * 256 + threadIdx.x;
    if (i >= 8 * HID * HID) return;
    int l = i >> 14;
    int k = (i >> 7) & 127;
    int n = i & 127;
    ushort h, m, lo;
    split3(Wst[i], h, m, lo);
    int ks = k >> 4, r = k & 15;
    size_t base = ((((size_t)l * 3) * 8 + ks) * 128 + n) * 16 + r;
    const size_t pstride = (size_t)8 * 128 * 16;  // one plane = 16384 ushort
    Wt4[base] = h;
    Wt4[base + pstride] = m;
    Wt4[base + 2 * pstride] = lo;
}

// ========== standalone dense GEMM (layer 0 only): H[NN,128] @ W -> T ==========

__global__ __launch_bounds__(256) void k_mfma_gemm(const float* __restrict__ H,
                                                   const ushort* __restrict__ Wt,
                                                   float* __restrict__ T) {
    int tid = threadIdx.x;
    int lane = tid & 63, w = tid >> 6;
    int l31 = lane & 31, lh = lane >> 5;
    int rowbase = blockIdx.x * 128;

    int grow = rowbase + w * 32 + l31;
    if (grow >= NN) grow = NN - 1;
    const float* arow = H + (size_t)grow * HID + lh * 8;
    const ushort* wbase = Wt + (size_t)l31 * 16 + lh * 8;

    f32x16 acc[4] = {};

#pragma unroll 2
    for (int s = 0; s < 8; ++s) {
        const float4* ap = (const float4*)(arow + s * 16);
        float4 f0 = ap[0], f1 = ap[1];
        float av[8] = {f0.x, f0.y, f0.z, f0.w, f1.x, f1.y, f1.z, f1.w};
        union { ushort u[8]; bf16x8 v; } ah, am, al;
#pragma unroll
        for (int q = 0; q < 8; ++q) split3(av[q], ah.u[q], am.u[q], al.u[q]);

        uint4 bf[3][4];
#pragma unroll
        for (int p = 0; p < 3; ++p)
#pragma unroll
            for (int c = 0; c < 4; ++c)
                bf[p][c] = *(const uint4*)(wbase + (((size_t)p * 8 + s) * 128 + c * 32) * 16);

#pragma unroll
        for (int c = 0; c < 4; ++c)
            acc[c] = __builtin_amdgcn_mfma_f32_32x32x16_bf16(ah.v, *(const bf16x8*)&bf[0][c], acc[c], 0, 0, 0);
#pragma unroll
        for (int c = 0; c < 4; ++c)
            acc[c] = __builtin_amdgcn_mfma_f32_32x32x16_bf16(ah.v, *(const bf16x8*)&bf[1][c], acc[c], 0, 0, 0);
#pragma unroll
        for (int c = 0; c < 4; ++c)
            acc[c] = __builtin_amdgcn_mfma_f32_32x32x16_bf16(am.v, *(const bf16x8*)&bf[0][c], acc[c], 0, 0, 0);
#pragma unroll
        for (int c = 0; c < 4; ++c)
            acc[c] = __builtin_amdgcn_mfma_f32_32x32x16_bf16(ah.v, *(const bf16x8*)&bf[2][c], acc[c], 0, 0, 0);
#pragma unroll
        for (int c = 0; c < 4; ++c)
            acc[c] = __builtin_amdgcn_mfma_f32_32x32x16_bf16(am.v, *(const bf16x8*)&bf[1][c], acc[c], 0, 0, 0);
#pragma unroll
        for (int c = 0; c < 4; ++c)
            acc[c] = __builtin_amdgcn_mfma_f32_32x32x16_bf16(al.v, *(const bf16x8*)&bf[0][c], acc[c], 0, 0, 0);
    }

#pragma unroll
    for (int c = 0; c < 4; ++c)
#pragma unroll
        for (int reg = 0; reg < 16; ++reg) {
            int r = (reg & 3) + 8 * (reg >> 2) + 4 * lh;
            int gr = rowbase + w * 32 + r;
            if (gr < NN)
                T[(size_t)gr * HID + c * 32 + l31] = acc[c][reg];
        }
}

// ---- shared gather-into-LDS phase: 64 nodes, NW waves, swizzled fp32 rows ----
__device__ __forceinline__ void gather_to_lds(const float* __restrict__ Tin,
                                              const int* __restrict__ rowptr,
                                              const int2* __restrict__ csr,
                                              const float* __restrict__ dinv,
                                              float4 bv, float* Hs,
                                              int rowbase, int w, int slot, int l31,
                                              int nodes_per_wave) {
    for (int i = 0; i < nodes_per_wave; ++i) {
        int lrow = w * nodes_per_wave + i;
        int node = rowbase + lrow;
        if (node >= NN) node = NN - 1;
        int beg = rowptr[node], end = rowptr[node + 1];
        float sn = dinv[node];

        float4 acc = {0.f, 0.f, 0.f, 0.f};
        if (slot == 1) {
            float4 tv = ((const float4*)(Tin + (size_t)node * HID))[l31];
            float s2 = sn * sn;
            acc.x = s2 * tv.x + bv.x;
            acc.y = s2 * tv.y + bv.y;
            acc.z = s2 * tv.z + bv.z;
            acc.w = s2 * tv.w + bv.w;
        }

        const int2 zed = make_int2(0, 0);
        int p = beg + slot;
        int2 e0 = (p < end) ? csr[p] : zed;
        int2 e1 = (p + 2 < end) ? csr[p + 2] : zed;
        int2 e2 = (p + 4 < end) ? csr[p + 4] : zed;
        int2 e3 = (p + 6 < end) ? csr[p + 6] : zed;
        for (; p < end; p += 8) {
            float4 u0 = ((const float4*)(Tin + (size_t)e0.x * HID))[l31];
            float4 u1 = ((const float4*)(Tin + (size_t)e1.x * HID))[l31];
            float4 u2 = ((const float4*)(Tin + (size_t)e2.x * HID))[l31];
            float4 u3 = ((const float4*)(Tin + (size_t)e3.x * HID))[l31];
            float w0 = __int_as_float(e0.y), w1 = __int_as_float(e1.y);
            float w2 = __int_as_float(e2.y), w3 = __int_as_float(e3.y);
            e0 = (p + 8 < end) ? csr[p + 8] : zed;
            e1 = (p + 10 < end) ? csr[p + 10] : zed;
            e2 = (p + 12 < end) ? csr[p + 12] : zed;
            e3 = (p + 14 < end) ? csr[p + 14] : zed;
            acc.x += w0 * u0.x; acc.y += w0 * u0.y; acc.z += w0 * u0.z; acc.w += w0 * u0.w;
            acc.x += w1 * u1.x; acc.y += w1 * u1.y; acc.z += w1 * u1.z; acc.w += w1 * u1.w;
            acc.x += w2 * u2.x; acc.y += w2 * u2.y; acc.z += w2 * u2.z; acc.w += w2 * u2.w;
            acc.x += w3 * u3.x; acc.y += w3 * u3.y; acc.z += w3 * u3.z; acc.w += w3 * u3.w;
        }

        acc.x += __shfl_xor(acc.x, 32, 64);
        acc.y += __shfl_xor(acc.y, 32, 64);
        acc.z += __shfl_xor(acc.z, 32, 64);
        acc.w += __shfl_xor(acc.w, 32, 64);

        if (slot == 0) {
            float4 r = acc;
            r.x = r.x > 0.f ? r.x : expm1f(r.x);
            r.y = r.y > 0.f ? r.y : expm1f(r.y);
            r.z = r.z > 0.f ? r.z : expm1f(r.z);
            r.w = r.w > 0.f ? r.w : expm1f(r.w);
            int byte = lrow * 512 + l31 * 16;
            byte ^= (lrow & 7) << 4;
            *(float4*)((char*)Hs + byte) = r;
        }
    }
}

// ========== FUSED: gather(layer l) -> H in LDS -> GEMM W_{l+1} -> Tout ==========
// 512 threads (8 waves), 64 nodes/block, Hs = 32 KB.
// Phase 1: wave w gathers 8 nodes (2 slots x 32 lanes, unroll-4 prefetch,
// bias+ELU), swizzled LDS write. 2x the latency-hiding waves of the 256-thr ver.
// Phase 2: wave w = rowgroup (w>>2) x colblock (w&3): 32 rows x 32 cols,
// A from LDS + split3 in-register, B streamed from Wt4 (L2-resident).

__global__ __launch_bounds__(512) void k_fused(const float* __restrict__ Tin,
                                               const ushort* __restrict__ Wt,
                                               const int* __restrict__ rowptr,
                                               const int2* __restrict__ csr,
                                               const float* __restrict__ dinv,
                                               const float* __restrict__ bias,
                                               float* __restrict__ Tout) {
    __shared__ float Hs[64 * 128];  // 32 KB
    int tid = threadIdx.x;
    int lane = tid & 63, w = tid >> 6;  // 8 waves
    int slot = lane >> 5, l31 = lane & 31;
    int rowbase = blockIdx.x * 64;

    float4 bv = ((const float4*)bias)[l31];

    gather_to_lds(Tin, rowptr, csr, dinv, bv, Hs, rowbase, w, slot, l31, 8);
    __syncthreads();

    // ---- phase 2: GEMM 64x128 tile over 8 waves (2 rowgroups x 4 colblocks) ----
    int lh = slot;                    // k-octet selector
    int rloc = (w >> 2) * 32 + l31;   // local A row
    int colb = w & 3;                 // column block (32)
    const ushort* wbase = Wt + ((size_t)(colb * 32) + l31) * 16 + lh * 8;

    f32x16 acc2 = {};

#pragma unroll 2
    for (int s = 0; s < 8; ++s) {
        int byte = rloc * 512 + s * 64 + lh * 32;
        int sw = (rloc & 7) << 4;
        float4 f0 = *(const float4*)((const char*)Hs + (byte ^ sw));
        float4 f1 = *(const float4*)((const char*)Hs + ((byte + 16) ^ sw));
        float av[8] = {f0.x, f0.y, f0.z, f0.w, f1.x, f1.y, f1.z, f1.w};
        union { ushort u[8]; bf16x8 v; } ah, am, al;
#pragma unroll
        for (int q = 0; q < 8; ++q) split3(av[q], ah.u[q], am.u[q], al.u[q]);

        uint4 bf[3];
#pragma unroll
        for (int p = 0; p < 3; ++p)
            bf[p] = *(const uint4*)(wbase + (((size_t)p * 8 + s) * 128) * 16);

        acc2 = __builtin_amdgcn_mfma_f32_32x32x16_bf16(ah.v, *(const bf16x8*)&bf[0], acc2, 0, 0, 0);
        acc2 = __builtin_amdgcn_mfma_f32_32x32x16_bf16(ah.v, *(const bf16x8*)&bf[1], acc2, 0, 0, 0);
        acc2 = __builtin_amdgcn_mfma_f32_32x32x16_bf16(am.v, *(const bf16x8*)&bf[0], acc2, 0, 0, 0);
        acc2 = __builtin_amdgcn_mfma_f32_32x32x16_bf16(ah.v, *(const bf16x8*)&bf[2], acc2, 0, 0, 0);
        acc2 = __builtin_amdgcn_mfma_f32_32x32x16_bf16(am.v, *(const bf16x8*)&bf[1], acc2, 0, 0, 0);
        acc2 = __builtin_amdgcn_mfma_f32_32x32x16_bf16(al.v, *(const bf16x8*)&bf[0], acc2, 0, 0, 0);
    }

    // C/D layout: col = lane&31, row = (reg&3) + 8*(reg>>2) + 4*(lane>>5)
#pragma unroll
    for (int reg = 0; reg < 16; ++reg) {
        int r = (reg & 3) + 8 * (reg >> 2) + 4 * lh;
        int gr = rowbase + (w >> 2) * 32 + r;
        if (gr < NN)
            Tout[(size_t)gr * HID + colb * 32 + l31] = acc2[reg];
    }
}

// ====== FUSED TAIL: gather(layer 7) -> H in LDS -> out-proj 128->10 -> T2 ======
// Same phase 1; phase 2: row = tid>>3, t8 = tid&7 owns k in [t8*16, +16);
// reduce over the 8-thread group via shfl_xor; t8==0 writes 10 classes.

__global__ __launch_bounds__(512) void k_fused_out(const float* __restrict__ Tin,
                                                   const float* __restrict__ W,
                                                   const int* __restrict__ rowptr,
                                                   const int2* __restrict__ csr,
                                                   const float* __restrict__ dinv,
                                                   const float* __restrict__ bias,
                                                   float* __restrict__ T2) {
    __shared__ float Hs[64 * 128];   // 32 KB
    __shared__ float Ws[128 * 11];   // 5.6 KB
    int tid = threadIdx.x;
    int lane = tid & 63, w = tid >> 6;
    int slot = lane >> 5, l31 = lane & 31;
    int rowbase = blockIdx.x * 64;

    for (int m = tid; m < HID * NCLS; m += 512) {
        int k = m / NCLS, c = m - k * NCLS;
        Ws[k * 11 + c] = W[m];
    }

    float4 bv = ((const float4*)bias)[l31];
    gather_to_lds(Tin, rowptr, csr, dinv, bv, Hs, rowbase, w, slot, l31, 8);
    __syncthreads();

    // ---- phase 2: T2[row] = Hs[row] . W ----
    int row = tid >> 3;      // 0..63
    int t8 = tid & 7;        // k-chunk of 16
    float acc[NCLS];
#pragma unroll
    for (int c = 0; c < NCLS; ++c) acc[c] = 0.f;
    int sw = (row & 7) << 4;
    int base = row * 512 + t8 * 64;
#pragma unroll
    for (int q = 0; q < 4; ++q) {
        float4 f = *(const float4*)((const char*)Hs + ((base + q * 16) ^ sw));
        float hv[4] = {f.x, f.y, f.z, f.w};
#pragma unroll
        for (int j = 0; j < 4; ++j) {
            const float* wr = &Ws[(t8 * 16 + q * 4 + j) * 11];
#pragma unroll
            for (int c = 0; c < NCLS; ++c) acc[c] += hv[j] * wr[c];
        }
    }
#pragma unroll
    for (int off = 4; off >= 1; off >>= 1) {
#pragma unroll
        for (int c = 0; c < NCLS; ++c) acc[c] += __shfl_xor(acc[c], off, 8);
    }
    int gr = rowbase + row;
    if (t8 == 0 && gr < NN) {
#pragma unroll
        for (int c = 0; c < NCLS; ++c) T2[(size_t)gr * T2S + c] = acc[c];
    }
}

__global__ __launch_bounds__(256) void k_gather_out(const float* __restrict__ T2,
                                                    float* __restrict__ out,
                                                    const int* __restrict__ rowptr,
                                                    const int2* __restrict__ csr,
                                                    const float* __restrict__ dinv,
                                                    const float* __restrict__ bias) {
    int lane = threadIdx.x & 63;
    int node = (blockIdx.x * 256 + threadIdx.x) >> 6;
    if (node >= NN) return;
    int slot = lane >> 4, c = lane & 15;
    int beg = rowptr[node], end = rowptr[node + 1];
    float acc = 0.f;
    if (c < NCLS) {
        for (int i = beg + slot; i < end; i += 4) {
            int2 e = csr[i];
            acc += __int_as_float(e.y) * T2[(size_t)e.x * T2S + c];
        }
    }
    acc += __shfl_xor(acc, 16, 64);
    acc += __shfl_xor(acc, 32, 64);
    if (slot == 0 && c < NCLS) {
        float sn = dinv[node];
        sn *= sn;
        out[node * NCLS + c] = acc + sn * T2[(size_t)node * T2S + c] + bias[c];
    }
}

// ================= launch =================

extern "C" void kernel_launch(void* const* d_in, const int* in_sizes, int n_in,
                              void* d_out, int out_size, void* d_ws, size_t ws_size,
                              hipStream_t stream) {
    (void)in_sizes; (void)n_in; (void)out_size; (void)ws_size;
    const float* x       = (const float*)d_in[0];
    const int*   edge    = (const int*)d_in[1];   // [2, NE] int32
    const float* W_stack = (const float*)d_in[2];
    const float* b_stack = (const float*)d_in[3];
    const float* W_out   = (const float*)d_in[4];
    const float* b_out   = (const float*)d_in[5];
    float* out = (float*)d_out;

    char* ws = (char*)d_ws;
    const size_t bigbuf = (size_t)NN * HID * sizeof(float);  // 25.6 MB
    float* X      = (float*)ws;
    float* Y      = (float*)(ws + bigbuf);
    char*  p      = ws + 2 * bigbuf;
    int2*  csr    = (int2*)p;              p += sizeof(int2) * NE;
    float* dinv   = (float*)p;             p += sizeof(float) * NN;
    int*   rowptr = (int*)p;               p += sizeof(int) * (NN + 1);
    int*   counts = (int*)p;               p += sizeof(int) * NN;    // reused as cursor
    int*   bsum   = (int*)p;               p += sizeof(int) * 256;
    p = (char*)(((size_t)p + 15) & ~(size_t)15);
    ushort* Wt4 = (ushort*)p;  p += sizeof(ushort) * 8 * 3 * HID * HID;  // 786 KB
    float* T2b  = (float*)p;   p += sizeof(float) * NN * T2S;            // 3.2 MB

    const int NB_N  = (NN + 255) / 256;
    const int NB_E  = (NE + 255) / 256;
    const int NB_G  = (NN + 127) / 128;        // 391 GEMM tiles (layer 0)
    const int NB_F  = (NN + 63) / 64;          // 782 fused tiles
    const int NB_A  = (NN * 64 + 255) / 256;
    const int NB_SW = (8 * HID * HID + 255) / 256;

    // ---- CSR build (per call) ----
    hipMemsetAsync(counts, 0, sizeof(int) * NN, stream);
    k_count<<<NB_E, 256, 0, stream>>>(edge, counts);
    k_scan1<<<NB_N, 256, 0, stream>>>(counts, rowptr, bsum, dinv);
    k_scan2<<<1, 256, 0, stream>>>(bsum, NB_N);
    k_scan3<<<NB_N, 256, 0, stream>>>(rowptr, bsum);
    k_fill<<<NB_E, 256, 0, stream>>>(edge, rowptr, counts, dinv, csr);

    // ---- one-time weight split ----
    k_split_w<<<NB_SW, 256, 0, stream>>>(W_stack, Wt4);

    // ---- layer 0 GEMM: T_0 = x . W0 ----
    k_mfma_gemm<<<NB_G, 256, 0, stream>>>(x, Wt4, Y);

    // ---- fused layers: gather(l) + GEMM W_{l+1}, l = 0..6 ----
    float* cur = Y;
    float* nxt = X;
    for (int l = 0; l < 7; ++l) {
        k_fused<<<NB_F, 512, 0, stream>>>(cur, Wt4 + (size_t)(l + 1) * 3 * HID * HID,
                                          rowptr, csr, dinv,
                                          b_stack + (size_t)l * HID, nxt);
        float* t = cur; cur = nxt; nxt = t;
    }

    // ---- fused tail: gather(bias 7) + out-proj -> T2 ----
    k_fused_out<<<NB_F, 512, 0, stream>>>(cur, W_out, rowptr, csr, dinv,
                                          b_stack + (size_t)7 * HID, T2b);

    // ---- final sparse layer ----
    k_gather_out<<<NB_A, 256, 0, stream>>>(T2b, out, rowptr, csr, dinv, b_out);
}

// Round 10
// 693.771 us; speedup vs baseline: 1.0568x; 1.0568x over previous
//
#include <hip/hip_runtime.h>
#include <math.h>

#define NN 50000
#define NE 600000
#define HID 128
#define NCLS 10
#define T2S 16  // padded row stride for the 10-class intermediate

typedef __bf16 bf16x8 __attribute__((ext_vector_type(8)));
typedef float f32x16 __attribute__((ext_vector_type(16)));

// Exact 3-way bf16 split: f == hi + mid + lo (bit-truncation splits are exact;
// fp32 has 24 mantissa bits, 3x bf16 planes carry 8+8+8 = all of them).
__device__ __forceinline__ void split3(float f, ushort& h, ushort& m, ushort& l) {
    unsigned uh = __float_as_uint(f) & 0xffff0000u;
    float fm = f - __uint_as_float(uh);
    unsigned um = __float_as_uint(fm) & 0xffff0000u;
    float fl = fm - __uint_as_float(um);
    h = (ushort)(uh >> 16);
    m = (ushort)(um >> 16);
    l = (ushort)(__float_as_uint(fl) >> 16);
}

// ================= graph prep: CSR by destination =================

__global__ __launch_bounds__(256) void k_count(const int* __restrict__ edge,
                                               int* __restrict__ counts) {
    int e = blockIdx.x * 256 + threadIdx.x;
    if (e < NE) atomicAdd(&counts[edge[NE + e]], 1);
}

__device__ __forceinline__ int wave_incl_scan(int x, int lane) {
#pragma unroll
    for (int off = 1; off < 64; off <<= 1) {
        int y = __shfl_up(x, off, 64);
        if (lane >= off) x += y;
    }
    return x;
}

__global__ __launch_bounds__(256) void k_scan1(const int* __restrict__ counts,
                                               int* __restrict__ rowptr,
                                               int* __restrict__ bsum,
                                               float* __restrict__ dinv) {
    __shared__ int ws[4];
    int tid = threadIdx.x;
    int i = blockIdx.x * 256 + tid;
    int lane = tid & 63, wv = tid >> 6;
    int v = (i < NN) ? counts[i] : 0;
    if (i < NN) dinv[i] = rsqrtf((float)(v + 1));
    int x = wave_incl_scan(v, lane);
    if (lane == 63) ws[wv] = x;
    __syncthreads();
    int off = 0;
    for (int j = 0; j < wv; ++j) off += ws[j];
    if (i < NN) rowptr[i] = off + x - v;
    if (tid == 255) bsum[blockIdx.x] = off + x;
}

__global__ __launch_bounds__(256) void k_scan2(int* __restrict__ bsum, int n) {
    __shared__ int ws[4];
    int tid = threadIdx.x;
    int lane = tid & 63, wv = tid >> 6;
    int v = (tid < n) ? bsum[tid] : 0;
    int x = wave_incl_scan(v, lane);
    if (lane == 63) ws[wv] = x;
    __syncthreads();
    int off = 0;
    for (int j = 0; j < wv; ++j) off += ws[j];
    __syncthreads();
    if (tid < n) bsum[tid] = off + x - v;
}

__global__ __launch_bounds__(256) void k_scan3(int* __restrict__ rowptr,
                                               const int* __restrict__ bsum) {
    int i = blockIdx.x * 256 + threadIdx.x;
    if (i < NN) rowptr[i] += bsum[blockIdx.x];
    if (i == 0) rowptr[NN] = NE;
}

// cursor == counts (still holds per-node counts after scan1); atomicSub gives
// slots count-1..0 -- order within a row is irrelevant for a sum.
__global__ __launch_bounds__(256) void k_fill(const int* __restrict__ edge,
                                              const int* __restrict__ rowptr,
                                              int* __restrict__ cursor,
                                              const float* __restrict__ dinv,
                                              int2* __restrict__ csr) {
    int e = blockIdx.x * 256 + threadIdx.x;
    if (e >= NE) return;
    int s = edge[e], d = edge[NE + e];
    int slot = atomicSub(&cursor[d], 1) - 1;
    csr[rowptr[d] + slot] = make_int2(s, __float_as_int(dinv[s] * dinv[d]));
}

// ================= one-time weight split =================
// W_stack [8][128 k][128 n] fp32 -> Wt4 [8][3 planes][8 ks][128 n][16] bf16.

__global__ __launch_bounds__(256) void k_split_w(const float* __restrict__ Wst,
                                                 ushort* __restrict__ Wt4) {
    int i = blockIdx.x * 256 + threadIdx.x;
    if (i >= 8 * HID * HID) return;
    int l = i >> 14;
    int k = (i >> 7) & 127;
    int n = i & 127;
    ushort h, m, lo;
    split3(Wst[i], h, m, lo);
    int ks = k >> 4, r = k & 15;
    size_t base = ((((size_t)l * 3) * 8 + ks) * 128 + n) * 16 + r;
    const size_t pstride = (size_t)8 * 128 * 16;  // one plane = 16384 ushort
    Wt4[base] = h;
    Wt4[base + pstride] = m;
    Wt4[base + 2 * pstride] = lo;
}

// ========== standalone dense GEMM (layer 0 only): H[NN,128] @ W -> T ==========

__global__ __launch_bounds__(256) void k_mfma_gemm(const float* __restrict__ H,
                                                   const ushort* __restrict__ Wt,
                                                   float* __restrict__ T) {
    int tid = threadIdx.x;
    int lane = tid & 63, w = tid >> 6;
    int l31 = lane & 31, lh = lane >> 5;
    int rowbase = blockIdx.x * 128;

    int grow = rowbase + w * 32 + l31;
    if (grow >= NN) grow = NN - 1;
    const float* arow = H + (size_t)grow * HID + lh * 8;
    const ushort* wbase = Wt + (size_t)l31 * 16 + lh * 8;

    f32x16 acc[4] = {};

#pragma unroll 2
    for (int s = 0; s < 8; ++s) {
        const float4* ap = (const float4*)(arow + s * 16);
        float4 f0 = ap[0], f1 = ap[1];
        float av[8] = {f0.x, f0.y, f0.z, f0.w, f1.x, f1.y, f1.z, f1.w};
        union { ushort u[8]; bf16x8 v; } ah, am, al;
#pragma unroll
        for (int q = 0; q < 8; ++q) split3(av[q], ah.u[q], am.u[q], al.u[q]);

        uint4 bf[3][4];
#pragma unroll
        for (int p = 0; p < 3; ++p)
#pragma unroll
            for (int c = 0; c < 4; ++c)
                bf[p][c] = *(const uint4*)(wbase + (((size_t)p * 8 + s) * 128 + c * 32) * 16);

#pragma unroll
        for (int c = 0; c < 4; ++c)
            acc[c] = __builtin_amdgcn_mfma_f32_32x32x16_bf16(ah.v, *(const bf16x8*)&bf[0][c], acc[c], 0, 0, 0);
#pragma unroll
        for (int c = 0; c < 4; ++c)
            acc[c] = __builtin_amdgcn_mfma_f32_32x32x16_bf16(ah.v, *(const bf16x8*)&bf[1][c], acc[c], 0, 0, 0);
#pragma unroll
        for (int c = 0; c < 4; ++c)
            acc[c] = __builtin_amdgcn_mfma_f32_32x32x16_bf16(am.v, *(const bf16x8*)&bf[0][c], acc[c], 0, 0, 0);
#pragma unroll
        for (int c = 0; c < 4; ++c)
            acc[c] = __builtin_amdgcn_mfma_f32_32x32x16_bf16(ah.v, *(const bf16x8*)&bf[2][c], acc[c], 0, 0, 0);
#pragma unroll
        for (int c = 0; c < 4; ++c)
            acc[c] = __builtin_amdgcn_mfma_f32_32x32x16_bf16(am.v, *(const bf16x8*)&bf[1][c], acc[c], 0, 0, 0);
#pragma unroll
        for (int c = 0; c < 4; ++c)
            acc[c] = __builtin_amdgcn_mfma_f32_32x32x16_bf16(al.v, *(const bf16x8*)&bf[0][c], acc[c], 0, 0, 0);
    }

#pragma unroll
    for (int c = 0; c < 4; ++c)
#pragma unroll
        for (int reg = 0; reg < 16; ++reg) {
            int r = (reg & 3) + 8 * (reg >> 2) + 4 * lh;
            int gr = rowbase + w * 32 + r;
            if (gr < NN)
                T[(size_t)gr * HID + c * 32 + l31] = acc[c][reg];
        }
}

// ---- shared gather-into-LDS phase: nodes -> swizzled fp32 rows in Hs ----
__device__ __forceinline__ void gather_to_lds(const float* __restrict__ Tin,
                                              const int* __restrict__ rowptr,
                                              const int2* __restrict__ csr,
                                              const float* __restrict__ dinv,
                                              float4 bv, float* Hs,
                                              int rowbase, int w, int slot, int l31,
                                              int nodes_per_wave) {
    for (int i = 0; i < nodes_per_wave; ++i) {
        int lrow = w * nodes_per_wave + i;
        int node = rowbase + lrow;
        if (node >= NN) node = NN - 1;
        int beg = rowptr[node], end = rowptr[node + 1];
        float sn = dinv[node];

        float4 acc = {0.f, 0.f, 0.f, 0.f};
        if (slot == 1) {
            float4 tv = ((const float4*)(Tin + (size_t)node * HID))[l31];
            float s2 = sn * sn;
            acc.x = s2 * tv.x + bv.x;
            acc.y = s2 * tv.y + bv.y;
            acc.z = s2 * tv.z + bv.z;
            acc.w = s2 * tv.w + bv.w;
        }

        const int2 zed = make_int2(0, 0);
        int p = beg + slot;
        int2 e0 = (p < end) ? csr[p] : zed;
        int2 e1 = (p + 2 < end) ? csr[p + 2] : zed;
        int2 e2 = (p + 4 < end) ? csr[p + 4] : zed;
        int2 e3 = (p + 6 < end) ? csr[p + 6] : zed;
        for (; p < end; p += 8) {
            float4 u0 = ((const float4*)(Tin + (size_t)e0.x * HID))[l31];
            float4 u1 = ((const float4*)(Tin + (size_t)e1.x * HID))[l31];
            float4 u2 = ((const float4*)(Tin + (size_t)e2.x * HID))[l31];
            float4 u3 = ((const float4*)(Tin + (size_t)e3.x * HID))[l31];
            float w0 = __int_as_float(e0.y), w1 = __int_as_float(e1.y);
            float w2 = __int_as_float(e2.y), w3 = __int_as_float(e3.y);
            e0 = (p + 8 < end) ? csr[p + 8] : zed;
            e1 = (p + 10 < end) ? csr[p + 10] : zed;
            e2 = (p + 12 < end) ? csr[p + 12] : zed;
            e3 = (p + 14 < end) ? csr[p + 14] : zed;
            acc.x += w0 * u0.x; acc.y += w0 * u0.y; acc.z += w0 * u0.z; acc.w += w0 * u0.w;
            acc.x += w1 * u1.x; acc.y += w1 * u1.y; acc.z += w1 * u1.z; acc.w += w1 * u1.w;
            acc.x += w2 * u2.x; acc.y += w2 * u2.y; acc.z += w2 * u2.z; acc.w += w2 * u2.w;
            acc.x += w3 * u3.x; acc.y += w3 * u3.y; acc.z += w3 * u3.z; acc.w += w3 * u3.w;
        }

        acc.x += __shfl_xor(acc.x, 32, 64);
        acc.y += __shfl_xor(acc.y, 32, 64);
        acc.z += __shfl_xor(acc.z, 32, 64);
        acc.w += __shfl_xor(acc.w, 32, 64);

        if (slot == 0) {
            float4 r = acc;
            r.x = r.x > 0.f ? r.x : expm1f(r.x);
            r.y = r.y > 0.f ? r.y : expm1f(r.y);
            r.z = r.z > 0.f ? r.z : expm1f(r.z);
            r.w = r.w > 0.f ? r.w : expm1f(r.w);
            int byte = lrow * 512 + l31 * 16;
            byte ^= (lrow & 7) << 4;
            *(float4*)((char*)Hs + byte) = r;
        }
    }
}

// ========== FUSED: gather(layer l) -> H in LDS -> GEMM W_{l+1} -> Tout ==========
// 256 threads, 32 nodes/block -> Hs = 16 KB, 1563 blocks (~6/CU): different
// blocks' gather and GEMM phases interleave on a CU, filling the memory-idle
// GEMM windows that capped the 64-node version at 2.9 TB/s.
// Phase 1: 4 waves x 8 nodes (R8's per-node code). Phase 2: waves 0-1 only,
// R8's proven wave geometry (32 rows x 64 cols, 2 indep accs); waves 2-3 retire.

__global__ __launch_bounds__(256) void k_fused(const float* __restrict__ Tin,
                                               const ushort* __restrict__ Wt,
                                               const int* __restrict__ rowptr,
                                               const int2* __restrict__ csr,
                                               const float* __restrict__ dinv,
                                               const float* __restrict__ bias,
                                               float* __restrict__ Tout) {
    __shared__ float Hs[32 * 128];  // 16 KB
    int tid = threadIdx.x;
    int lane = tid & 63, w = tid >> 6;  // 4 waves
    int slot = lane >> 5, l31 = lane & 31;
    int rowbase = blockIdx.x * 32;

    float4 bv = ((const float4*)bias)[l31];

    gather_to_lds(Tin, rowptr, csr, dinv, bv, Hs, rowbase, w, slot, l31, 8);
    __syncthreads();

    if (w >= 2) return;  // phase 2 needs only 2 waves

    // ---- phase 2: GEMM 32x128 tile, wave = column half ----
    int lh = slot;                    // k-octet selector
    int colh = w;                     // column half (64)
    const ushort* wbase = Wt + ((size_t)(colh * 64) + l31) * 16 + lh * 8;

    f32x16 acc2[2] = {};

#pragma unroll 2
    for (int s = 0; s < 8; ++s) {
        int byte = l31 * 512 + s * 64 + lh * 32;
        int sw = (l31 & 7) << 4;
        float4 f0 = *(const float4*)((const char*)Hs + (byte ^ sw));
        float4 f1 = *(const float4*)((const char*)Hs + ((byte + 16) ^ sw));
        float av[8] = {f0.x, f0.y, f0.z, f0.w, f1.x, f1.y, f1.z, f1.w};
        union { ushort u[8]; bf16x8 v; } ah, am, al;
#pragma unroll
        for (int q = 0; q < 8; ++q) split3(av[q], ah.u[q], am.u[q], al.u[q]);

        uint4 bf[3][2];
#pragma unroll
        for (int p = 0; p < 3; ++p)
#pragma unroll
            for (int c = 0; c < 2; ++c)
                bf[p][c] = *(const uint4*)(wbase + (((size_t)p * 8 + s) * 128 + c * 32) * 16);

#pragma unroll
        for (int c = 0; c < 2; ++c)
            acc2[c] = __builtin_amdgcn_mfma_f32_32x32x16_bf16(ah.v, *(const bf16x8*)&bf[0][c], acc2[c], 0, 0, 0);
#pragma unroll
        for (int c = 0; c < 2; ++c)
            acc2[c] = __builtin_amdgcn_mfma_f32_32x32x16_bf16(ah.v, *(const bf16x8*)&bf[1][c], acc2[c], 0, 0, 0);
#pragma unroll
        for (int c = 0; c < 2; ++c)
            acc2[c] = __builtin_amdgcn_mfma_f32_32x32x16_bf16(am.v, *(const bf16x8*)&bf[0][c], acc2[c], 0, 0, 0);
#pragma unroll
        for (int c = 0; c < 2; ++c)
            acc2[c] = __builtin_amdgcn_mfma_f32_32x32x16_bf16(ah.v, *(const bf16x8*)&bf[2][c], acc2[c], 0, 0, 0);
#pragma unroll
        for (int c = 0; c < 2; ++c)
            acc2[c] = __builtin_amdgcn_mfma_f32_32x32x16_bf16(am.v, *(const bf16x8*)&bf[1][c], acc2[c], 0, 0, 0);
#pragma unroll
        for (int c = 0; c < 2; ++c)
            acc2[c] = __builtin_amdgcn_mfma_f32_32x32x16_bf16(al.v, *(const bf16x8*)&bf[0][c], acc2[c], 0, 0, 0);
    }

    // C/D layout: col = lane&31, row = (reg&3) + 8*(reg>>2) + 4*(lane>>5)
#pragma unroll
    for (int c = 0; c < 2; ++c)
#pragma unroll
        for (int reg = 0; reg < 16; ++reg) {
            int r = (reg & 3) + 8 * (reg >> 2) + 4 * lh;
            int gr = rowbase + r;
            if (gr < NN)
                Tout[(size_t)gr * HID + colh * 64 + c * 32 + l31] = acc2[c][reg];
        }
}

// ====== FUSED TAIL: gather(layer 7) -> H in LDS -> out-proj 128->10 -> T2 ======
// 256 threads, 32 nodes. Phase 2: row = tid>>3 (0..31), t8 = tid&7 owns k in
// [t8*16,+16); shfl_xor reduce over the 8-group; t8==0 writes 10 classes.

__global__ __launch_bounds__(256) void k_fused_out(const float* __restrict__ Tin,
                                                   const float* __restrict__ W,
                                                   const int* __restrict__ rowptr,
                                                   const int2* __restrict__ csr,
                                                   const float* __restrict__ dinv,
                                                   const float* __restrict__ bias,
                                                   float* __restrict__ T2) {
    __shared__ float Hs[32 * 128];   // 16 KB
    __shared__ float Ws[128 * 11];   // 5.6 KB
    int tid = threadIdx.x;
    int lane = tid & 63, w = tid >> 6;
    int slot = lane >> 5, l31 = lane & 31;
    int rowbase = blockIdx.x * 32;

    for (int m = tid; m < HID * NCLS; m += 256) {
        int k = m / NCLS, c = m - k * NCLS;
        Ws[k * 11 + c] = W[m];
    }

    float4 bv = ((const float4*)bias)[l31];
    gather_to_lds(Tin, rowptr, csr, dinv, bv, Hs, rowbase, w, slot, l31, 8);
    __syncthreads();

    // ---- phase 2: T2[row] = Hs[row] . W ----
    int row = tid >> 3;      // 0..31
    int t8 = tid & 7;        // k-chunk of 16
    float acc[NCLS];
#pragma unroll
    for (int c = 0; c < NCLS; ++c) acc[c] = 0.f;
    int sw = (row & 7) << 4;
    int base = row * 512 + t8 * 64;
#pragma unroll
    for (int q = 0; q < 4; ++q) {
        float4 f = *(const float4*)((const char*)Hs + ((base + q * 16) ^ sw));
        float hv[4] = {f.x, f.y, f.z, f.w};
#pragma unroll
        for (int j = 0; j < 4; ++j) {
            const float* wr = &Ws[(t8 * 16 + q * 4 + j) * 11];
#pragma unroll
            for (int c = 0; c < NCLS; ++c) acc[c] += hv[j] * wr[c];
        }
    }
#pragma unroll
    for (int off = 4; off >= 1; off >>= 1) {
#pragma unroll
        for (int c = 0; c < NCLS; ++c) acc[c] += __shfl_xor(acc[c], off, 8);
    }
    int gr = rowbase + row;
    if (t8 == 0 && gr < NN) {
#pragma unroll
        for (int c = 0; c < NCLS; ++c) T2[(size_t)gr * T2S + c] = acc[c];
    }
}

__global__ __launch_bounds__(256) void k_gather_out(const float* __restrict__ T2,
                                                    float* __restrict__ out,
                                                    const int* __restrict__ rowptr,
                                                    const int2* __restrict__ csr,
                                                    const float* __restrict__ dinv,
                                                    const float* __restrict__ bias) {
    int lane = threadIdx.x & 63;
    int node = (blockIdx.x * 256 + threadIdx.x) >> 6;
    if (node >= NN) return;
    int slot = lane >> 4, c = lane & 15;
    int beg = rowptr[node], end = rowptr[node + 1];
    float acc = 0.f;
    if (c < NCLS) {
        for (int i = beg + slot; i < end; i += 4) {
            int2 e = csr[i];
            acc += __int_as_float(e.y) * T2[(size_t)e.x * T2S + c];
        }
    }
    acc += __shfl_xor(acc, 16, 64);
    acc += __shfl_xor(acc, 32, 64);
    if (slot == 0 && c < NCLS) {
        float sn = dinv[node];
        sn *= sn;
        out[node * NCLS + c] = acc + sn * T2[(size_t)node * T2S + c] + bias[c];
    }
}

// ================= launch =================

extern "C" void kernel_launch(void* const* d_in, const int* in_sizes, int n_in,
                              void* d_out, int out_size, void* d_ws, size_t ws_size,
                              hipStream_t stream) {
    (void)in_sizes; (void)n_in; (void)out_size; (void)ws_size;
    const float* x       = (const float*)d_in[0];
    const int*   edge    = (const int*)d_in[1];   // [2, NE] int32
    const float* W_stack = (const float*)d_in[2];
    const float* b_stack = (const float*)d_in[3];
    const float* W_out   = (const float*)d_in[4];
    const float* b_out   = (const float*)d_in[5];
    float* out = (float*)d_out;

    char* ws = (char*)d_ws;
    const size_t bigbuf = (size_t)NN * HID * sizeof(float);  // 25.6 MB
    float* X      = (float*)ws;
    float* Y      = (float*)(ws + bigbuf);
    char*  p      = ws + 2 * bigbuf;
    int2*  csr    = (int2*)p;              p += sizeof(int2) * NE;
    float* dinv   = (float*)p;             p += sizeof(float) * NN;
    int*   rowptr = (int*)p;               p += sizeof(int) * (NN + 1);
    int*   counts = (int*)p;               p += sizeof(int) * NN;    // reused as cursor
    int*   bsum   = (int*)p;               p += sizeof(int) * 256;
    p = (char*)(((size_t)p + 15) & ~(size_t)15);
    ushort* Wt4 = (ushort*)p;  p += sizeof(ushort) * 8 * 3 * HID * HID;  // 786 KB
    float* T2b  = (float*)p;   p += sizeof(float) * NN * T2S;            // 3.2 MB

    const int NB_N  = (NN + 255) / 256;
    const int NB_E  = (NE + 255) / 256;
    const int NB_G  = (NN + 127) / 128;        // 391 GEMM tiles (layer 0)
    const int NB_F  = (NN + 31) / 32;          // 1563 fused tiles
    const int NB_A  = (NN * 64 + 255) / 256;
    const int NB_SW = (8 * HID * HID + 255) / 256;

    // ---- CSR build (per call) ----
    hipMemsetAsync(counts, 0, sizeof(int) * NN, stream);
    k_count<<<NB_E, 256, 0, stream>>>(edge, counts);
    k_scan1<<<NB_N, 256, 0, stream>>>(counts, rowptr, bsum, dinv);
    k_scan2<<<1, 256, 0, stream>>>(bsum, NB_N);
    k_scan3<<<NB_N, 256, 0, stream>>>(rowptr, bsum);
    k_fill<<<NB_E, 256, 0, stream>>>(edge, rowptr, counts, dinv, csr);

    // ---- one-time weight split ----
    k_split_w<<<NB_SW, 256, 0, stream>>>(W_stack, Wt4);

    // ---- layer 0 GEMM: T_0 = x . W0 ----
    k_mfma_gemm<<<NB_G, 256, 0, stream>>>(x, Wt4, Y);

    // ---- fused layers: gather(l) + GEMM W_{l+1}, l = 0..6 ----
    float* cur = Y;
    float* nxt = X;
    for (int l = 0; l < 7; ++l) {
        k_fused<<<NB_F, 256, 0, stream>>>(cur, Wt4 + (size_t)(l + 1) * 3 * HID * HID,
                                          rowptr, csr, dinv,
                                          b_stack + (size_t)l * HID, nxt);
        float* t = cur; cur = nxt; nxt = t;
    }

    // ---- fused tail: gather(bias 7) + out-proj -> T2 ----
    k_fused_out<<<NB_F, 256, 0, stream>>>(cur, W_out, rowptr, csr, dinv,
                                          b_stack + (size_t)7 * HID, T2b);

    // ---- final sparse layer ----
    k_gather_out<<<NB_A, 256, 0, stream>>>(T2b, out, rowptr, csr, dinv, b_out);
}

// Round 11
// 648.158 us; speedup vs baseline: 1.1311x; 1.0704x over previous
//
#include <hip/hip_runtime.h>
#include <math.h>

#define NN 50000
#define NE 600000
#define HID 128
#define NCLS 10
#define T2S 16  // padded row stride for the 10-class intermediate

typedef __bf16 bf16x8 __attribute__((ext_vector_type(8)));
typedef float f32x16 __attribute__((ext_vector_type(16)));

// Exact 3-way bf16 split: f == hi + mid + lo (bit-truncation splits are exact;
// fp32 has 24 mantissa bits, 3x bf16 planes carry 8+8+8 = all of them).
__device__ __forceinline__ void split3(float f, ushort& h, ushort& m, ushort& l) {
    unsigned uh = __float_as_uint(f) & 0xffff0000u;
    float fm = f - __uint_as_float(uh);
    unsigned um = __float_as_uint(fm) & 0xffff0000u;
    float fl = fm - __uint_as_float(um);
    h = (ushort)(uh >> 16);
    m = (ushort)(um >> 16);
    l = (ushort)(__float_as_uint(fl) >> 16);
}

// ================= graph prep: CSR by destination =================

__global__ __launch_bounds__(256) void k_count(const int* __restrict__ edge,
                                               int* __restrict__ counts) {
    int e = blockIdx.x * 256 + threadIdx.x;
    if (e < NE) atomicAdd(&counts[edge[NE + e]], 1);
}

__device__ __forceinline__ int wave_incl_scan(int x, int lane) {
#pragma unroll
    for (int off = 1; off < 64; off <<= 1) {
        int y = __shfl_up(x, off, 64);
        if (lane >= off) x += y;
    }
    return x;
}

__global__ __launch_bounds__(256) void k_scan1(const int* __restrict__ counts,
                                               int* __restrict__ rowptr,
                                               int* __restrict__ bsum,
                                               float* __restrict__ dinv) {
    __shared__ int ws[4];
    int tid = threadIdx.x;
    int i = blockIdx.x * 256 + tid;
    int lane = tid & 63, wv = tid >> 6;
    int v = (i < NN) ? counts[i] : 0;
    if (i < NN) dinv[i] = rsqrtf((float)(v + 1));
    int x = wave_incl_scan(v, lane);
    if (lane == 63) ws[wv] = x;
    __syncthreads();
    int off = 0;
    for (int j = 0; j < wv; ++j) off += ws[j];
    if (i < NN) rowptr[i] = off + x - v;
    if (tid == 255) bsum[blockIdx.x] = off + x;
}

__global__ __launch_bounds__(256) void k_scan2(int* __restrict__ bsum, int n) {
    __shared__ int ws[4];
    int tid = threadIdx.x;
    int lane = tid & 63, wv = tid >> 6;
    int v = (tid < n) ? bsum[tid] : 0;
    int x = wave_incl_scan(v, lane);
    if (lane == 63) ws[wv] = x;
    __syncthreads();
    int off = 0;
    for (int j = 0; j < wv; ++j) off += ws[j];
    __syncthreads();
    if (tid < n) bsum[tid] = off + x - v;
}

__global__ __launch_bounds__(256) void k_scan3(int* __restrict__ rowptr,
                                               const int* __restrict__ bsum) {
    int i = blockIdx.x * 256 + threadIdx.x;
    if (i < NN) rowptr[i] += bsum[blockIdx.x];
    if (i == 0) rowptr[NN] = NE;
}

// cursor == counts (still holds per-node counts after scan1); atomicSub gives
// slots count-1..0 -- order within a row is irrelevant for a sum.
__global__ __launch_bounds__(256) void k_fill(const int* __restrict__ edge,
                                              const int* __restrict__ rowptr,
                                              int* __restrict__ cursor,
                                              const float* __restrict__ dinv,
                                              int2* __restrict__ csr) {
    int e = blockIdx.x * 256 + threadIdx.x;
    if (e >= NE) return;
    int s = edge[e], d = edge[NE + e];
    int slot = atomicSub(&cursor[d], 1) - 1;
    csr[rowptr[d] + slot] = make_int2(s, __float_as_int(dinv[s] * dinv[d]));
}

// ================= one-time weight split =================
// W_stack [8][128 k][128 n] fp32 -> Wt4 [8][3 planes][8 ks][128 n][16] bf16.

__global__ __launch_bounds__(256) void k_split_w(const float* __restrict__ Wst,
                                                 ushort* __restrict__ Wt4) {
    int i = blockIdx.x * 256 + threadIdx.x;
    if (i >= 8 * HID * HID) return;
    int l = i >> 14;
    int k = (i >> 7) & 127;
    int n = i & 127;
    ushort h, m, lo;
    split3(Wst[i], h, m, lo);
    int ks = k >> 4, r = k & 15;
    size_t base = ((((size_t)l * 3) * 8 + ks) * 128 + n) * 16 + r;
    const size_t pstride = (size_t)8 * 128 * 16;  // one plane = 16384 ushort
    Wt4[base] = h;
    Wt4[base + pstride] = m;
    Wt4[base + 2 * pstride] = lo;
}

// ========== standalone dense GEMM (layer 0 only): H[NN,128] @ W -> T ==========

__global__ __launch_bounds__(256) void k_mfma_gemm(const float* __restrict__ H,
                                                   const ushort* __restrict__ Wt,
                                                   float* __restrict__ T) {
    int tid = threadIdx.x;
    int lane = tid & 63, w = tid >> 6;
    int l31 = lane & 31, lh = lane >> 5;
    int rowbase = blockIdx.x * 128;

    int grow = rowbase + w * 32 + l31;
    if (grow >= NN) grow = NN - 1;
    const float* arow = H + (size_t)grow * HID + lh * 8;
    const ushort* wbase = Wt + (size_t)l31 * 16 + lh * 8;

    f32x16 acc[4] = {};

#pragma unroll 2
    for (int s = 0; s < 8; ++s) {
        const float4* ap = (const float4*)(arow + s * 16);
        float4 f0 = ap[0], f1 = ap[1];
        float av[8] = {f0.x, f0.y, f0.z, f0.w, f1.x, f1.y, f1.z, f1.w};
        union { ushort u[8]; bf16x8 v; } ah, am, al;
#pragma unroll
        for (int q = 0; q < 8; ++q) split3(av[q], ah.u[q], am.u[q], al.u[q]);

        uint4 bf[3][4];
#pragma unroll
        for (int p = 0; p < 3; ++p)
#pragma unroll
            for (int c = 0; c < 4; ++c)
                bf[p][c] = *(const uint4*)(wbase + (((size_t)p * 8 + s) * 128 + c * 32) * 16);

#pragma unroll
        for (int c = 0; c < 4; ++c)
            acc[c] = __builtin_amdgcn_mfma_f32_32x32x16_bf16(ah.v, *(const bf16x8*)&bf[0][c], acc[c], 0, 0, 0);
#pragma unroll
        for (int c = 0; c < 4; ++c)
            acc[c] = __builtin_amdgcn_mfma_f32_32x32x16_bf16(ah.v, *(const bf16x8*)&bf[1][c], acc[c], 0, 0, 0);
#pragma unroll
        for (int c = 0; c < 4; ++c)
            acc[c] = __builtin_amdgcn_mfma_f32_32x32x16_bf16(am.v, *(const bf16x8*)&bf[0][c], acc[c], 0, 0, 0);
#pragma unroll
        for (int c = 0; c < 4; ++c)
            acc[c] = __builtin_amdgcn_mfma_f32_32x32x16_bf16(ah.v, *(const bf16x8*)&bf[2][c], acc[c], 0, 0, 0);
#pragma unroll
        for (int c = 0; c < 4; ++c)
            acc[c] = __builtin_amdgcn_mfma_f32_32x32x16_bf16(am.v, *(const bf16x8*)&bf[1][c], acc[c], 0, 0, 0);
#pragma unroll
        for (int c = 0; c < 4; ++c)
            acc[c] = __builtin_amdgcn_mfma_f32_32x32x16_bf16(al.v, *(const bf16x8*)&bf[0][c], acc[c], 0, 0, 0);
    }

#pragma unroll
    for (int c = 0; c < 4; ++c)
#pragma unroll
        for (int reg = 0; reg < 16; ++reg) {
            int r = (reg & 3) + 8 * (reg >> 2) + 4 * lh;
            int gr = rowbase + w * 32 + r;
            if (gr < NN)
                T[(size_t)gr * HID + c * 32 + l31] = acc[c][reg];
        }
}

// ---- gather-into-LDS, 2 independent node-chains per wave ----
// Each 32-lane half (h = lane>>5) owns one node: lane covers 4 cols (float4).
// No cross-lane reduce. Next node's metadata (rowptr/dinv/self-row) prefetched
// before the current node's edge loop so prologue latency overlaps streaming.
// Wave w covers rows [w*16, w*16+16); half h takes rows w*16 + 2i + h.
__device__ __forceinline__ void gather2_to_lds(const float* __restrict__ Tin,
                                               const int* __restrict__ rowptr,
                                               const int2* __restrict__ csr,
                                               const float* __restrict__ dinv,
                                               float4 bv, float* Hs,
                                               int rowbase, int w, int h, int l31) {
    int lrow = w * 16 + h;
    int node = rowbase + lrow;
    if (node >= NN) node = NN - 1;
    int beg = rowptr[node], end = rowptr[node + 1];
    float sn = dinv[node];
    float4 tv = ((const float4*)(Tin + (size_t)node * HID))[l31];

    for (int i = 0; i < 8; ++i) {
        // prefetch next node's metadata (independent chain head)
        int nlrow = lrow + 2;
        int nbeg = 0, nend = 0;
        float nsn = 0.f;
        float4 ntv = {0.f, 0.f, 0.f, 0.f};
        if (i < 7) {
            int nnode = rowbase + nlrow;
            if (nnode >= NN) nnode = NN - 1;
            nbeg = rowptr[nnode];
            nend = rowptr[nnode + 1];
            nsn = dinv[nnode];
            ntv = ((const float4*)(Tin + (size_t)nnode * HID))[l31];
        }

        float s2 = sn * sn;
        float4 acc;
        acc.x = s2 * tv.x + bv.x;
        acc.y = s2 * tv.y + bv.y;
        acc.z = s2 * tv.z + bv.z;
        acc.w = s2 * tv.w + bv.w;

        const int2 zed = make_int2(0, 0);  // norm bits 0 -> weight 0
        int p = beg;
        int2 e0 = (p < end) ? csr[p] : zed;
        int2 e1 = (p + 1 < end) ? csr[p + 1] : zed;
        int2 e2 = (p + 2 < end) ? csr[p + 2] : zed;
        int2 e3 = (p + 3 < end) ? csr[p + 3] : zed;
        for (; p < end; p += 4) {
            float4 u0 = ((const float4*)(Tin + (size_t)e0.x * HID))[l31];
            float4 u1 = ((const float4*)(Tin + (size_t)e1.x * HID))[l31];
            float4 u2 = ((const float4*)(Tin + (size_t)e2.x * HID))[l31];
            float4 u3 = ((const float4*)(Tin + (size_t)e3.x * HID))[l31];
            float w0 = __int_as_float(e0.y), w1 = __int_as_float(e1.y);
            float w2 = __int_as_float(e2.y), w3 = __int_as_float(e3.y);
            e0 = (p + 4 < end) ? csr[p + 4] : zed;
            e1 = (p + 5 < end) ? csr[p + 5] : zed;
            e2 = (p + 6 < end) ? csr[p + 6] : zed;
            e3 = (p + 7 < end) ? csr[p + 7] : zed;
            acc.x += w0 * u0.x; acc.y += w0 * u0.y; acc.z += w0 * u0.z; acc.w += w0 * u0.w;
            acc.x += w1 * u1.x; acc.y += w1 * u1.y; acc.z += w1 * u1.z; acc.w += w1 * u1.w;
            acc.x += w2 * u2.x; acc.y += w2 * u2.y; acc.z += w2 * u2.z; acc.w += w2 * u2.w;
            acc.x += w3 * u3.x; acc.y += w3 * u3.y; acc.z += w3 * u3.z; acc.w += w3 * u3.w;
        }

        acc.x = acc.x > 0.f ? acc.x : expm1f(acc.x);
        acc.y = acc.y > 0.f ? acc.y : expm1f(acc.y);
        acc.z = acc.z > 0.f ? acc.z : expm1f(acc.z);
        acc.w = acc.w > 0.f ? acc.w : expm1f(acc.w);
        int byte = lrow * 512 + l31 * 16;
        byte ^= (lrow & 7) << 4;
        *(float4*)((char*)Hs + byte) = acc;

        lrow = nlrow; beg = nbeg; end = nend; sn = nsn; tv = ntv;
    }
}

// ========== FUSED: gather(layer l) -> H in LDS -> GEMM W_{l+1} -> Tout ==========
// R8 geometry: 256 threads, 64 nodes/block, Hs = 32 KB, 782 blocks.
// Phase 1: 2-chain gather (above). Phase 2: wave w = rowgroup (w>>1) x
// colhalf (w&1): 32 rows x 64 cols, A from LDS + split3 in-register,
// B streamed from Wt4 (L2-resident).

__global__ __launch_bounds__(256, 4) void k_fused(const float* __restrict__ Tin,
                                                  const ushort* __restrict__ Wt,
                                                  const int* __restrict__ rowptr,
                                                  const int2* __restrict__ csr,
                                                  const float* __restrict__ dinv,
                                                  const float* __restrict__ bias,
                                                  float* __restrict__ Tout) {
    __shared__ float Hs[64 * 128];  // 32 KB
    int tid = threadIdx.x;
    int lane = tid & 63, w = tid >> 6;  // 4 waves
    int hh = lane >> 5, l31 = lane & 31;
    int rowbase = blockIdx.x * 64;

    float4 bv = ((const float4*)bias)[l31];

    gather2_to_lds(Tin, rowptr, csr, dinv, bv, Hs, rowbase, w, hh, l31);
    __syncthreads();

    // ---- phase 2: GEMM 64x128 tile over 4 waves ----
    int lh = hh;                      // k-octet selector
    int rloc = (w >> 1) * 32 + l31;   // local A row
    int colh = w & 1;                 // column half (64)
    const ushort* wbase = Wt + ((size_t)(colh * 64) + l31) * 16 + lh * 8;

    f32x16 acc2[2] = {};

#pragma unroll 2
    for (int s = 0; s < 8; ++s) {
        int byte = rloc * 512 + s * 64 + lh * 32;
        int sw = (rloc & 7) << 4;
        float4 f0 = *(const float4*)((const char*)Hs + (byte ^ sw));
        float4 f1 = *(const float4*)((const char*)Hs + ((byte + 16) ^ sw));
        float av[8] = {f0.x, f0.y, f0.z, f0.w, f1.x, f1.y, f1.z, f1.w};
        union { ushort u[8]; bf16x8 v; } ah, am, al;
#pragma unroll
        for (int q = 0; q < 8; ++q) split3(av[q], ah.u[q], am.u[q], al.u[q]);

        uint4 bf[3][2];
#pragma unroll
        for (int p = 0; p < 3; ++p)
#pragma unroll
            for (int c = 0; c < 2; ++c)
                bf[p][c] = *(const uint4*)(wbase + (((size_t)p * 8 + s) * 128 + c * 32) * 16);

#pragma unroll
        for (int c = 0; c < 2; ++c)
            acc2[c] = __builtin_amdgcn_mfma_f32_32x32x16_bf16(ah.v, *(const bf16x8*)&bf[0][c], acc2[c], 0, 0, 0);
#pragma unroll
        for (int c = 0; c < 2; ++c)
            acc2[c] = __builtin_amdgcn_mfma_f32_32x32x16_bf16(ah.v, *(const bf16x8*)&bf[1][c], acc2[c], 0, 0, 0);
#pragma unroll
        for (int c = 0; c < 2; ++c)
            acc2[c] = __builtin_amdgcn_mfma_f32_32x32x16_bf16(am.v, *(const bf16x8*)&bf[0][c], acc2[c], 0, 0, 0);
#pragma unroll
        for (int c = 0; c < 2; ++c)
            acc2[c] = __builtin_amdgcn_mfma_f32_32x32x16_bf16(ah.v, *(const bf16x8*)&bf[2][c], acc2[c], 0, 0, 0);
#pragma unroll
        for (int c = 0; c < 2; ++c)
            acc2[c] = __builtin_amdgcn_mfma_f32_32x32x16_bf16(am.v, *(const bf16x8*)&bf[1][c], acc2[c], 0, 0, 0);
#pragma unroll
        for (int c = 0; c < 2; ++c)
            acc2[c] = __builtin_amdgcn_mfma_f32_32x32x16_bf16(al.v, *(const bf16x8*)&bf[0][c], acc2[c], 0, 0, 0);
    }

    // C/D layout: col = lane&31, row = (reg&3) + 8*(reg>>2) + 4*(lane>>5)
#pragma unroll
    for (int c = 0; c < 2; ++c)
#pragma unroll
        for (int reg = 0; reg < 16; ++reg) {
            int r = (reg & 3) + 8 * (reg >> 2) + 4 * lh;
            int gr = rowbase + (w >> 1) * 32 + r;
            if (gr < NN)
                Tout[(size_t)gr * HID + colh * 64 + c * 32 + l31] = acc2[c][reg];
        }
}

// ====== FUSED TAIL: gather(layer 7) -> H in LDS -> out-proj 128->10 -> T2 ======
// Same 64-node phase 1. Phase 2: row = tid>>2 (0..63), t4 = tid&3 owns 8
// interleaved 16B chunks (c = q*4 + t4); shfl_xor reduce over the 4-group.

__global__ __launch_bounds__(256, 4) void k_fused_out(const float* __restrict__ Tin,
                                                      const float* __restrict__ W,
                                                      const int* __restrict__ rowptr,
                                                      const int2* __restrict__ csr,
                                                      const float* __restrict__ dinv,
                                                      const float* __restrict__ bias,
                                                      float* __restrict__ T2) {
    __shared__ float Hs[64 * 128];   // 32 KB
    __shared__ float Ws[128 * 11];   // 5.6 KB
    int tid = threadIdx.x;
    int lane = tid & 63, w = tid >> 6;
    int hh = lane >> 5, l31 = lane & 31;
    int rowbase = blockIdx.x * 64;

    for (int m = tid; m < HID * NCLS; m += 256) {
        int k = m / NCLS, c = m - k * NCLS;
        Ws[k * 11 + c] = W[m];
    }

    float4 bv = ((const float4*)bias)[l31];
    gather2_to_lds(Tin, rowptr, csr, dinv, bv, Hs, rowbase, w, hh, l31);
    __syncthreads();

    // ---- phase 2: T2[row] = Hs[row] . W ----
    int row = tid >> 2;      // 0..63
    int t4 = tid & 3;
    float acc[NCLS];
#pragma unroll
    for (int c = 0; c < NCLS; ++c) acc[c] = 0.f;
    int sw = (row & 7) << 4;
#pragma unroll
    for (int q = 0; q < 8; ++q) {
        int c16 = q * 4 + t4;  // 16B chunk index 0..31, interleaved across t4
        float4 f = *(const float4*)((const char*)Hs + ((row * 512 + c16 * 16) ^ sw));
        float hv[4] = {f.x, f.y, f.z, f.w};
#pragma unroll
        for (int j = 0; j < 4; ++j) {
            const float* wr = &Ws[(c16 * 4 + j) * 11];
#pragma unroll
            for (int c = 0; c < NCLS; ++c) acc[c] += hv[j] * wr[c];
        }
    }
#pragma unroll
    for (int off = 2; off >= 1; off >>= 1) {
#pragma unroll
        for (int c = 0; c < NCLS; ++c) acc[c] += __shfl_xor(acc[c], off, 4);
    }
    int gr = rowbase + row;
    if (t4 == 0 && gr < NN) {
#pragma unroll
        for (int c = 0; c < NCLS; ++c) T2[(size_t)gr * T2S + c] = acc[c];
    }
}

__global__ __launch_bounds__(256) void k_gather_out(const float* __restrict__ T2,
                                                    float* __restrict__ out,
                                                    const int* __restrict__ rowptr,
                                                    const int2* __restrict__ csr,
                                                    const float* __restrict__ dinv,
                                                    const float* __restrict__ bias) {
    int lane = threadIdx.x & 63;
    int node = (blockIdx.x * 256 + threadIdx.x) >> 6;
    if (node >= NN) return;
    int slot = lane >> 4, c = lane & 15;
    int beg = rowptr[node], end = rowptr[node + 1];
    float acc = 0.f;
    if (c < NCLS) {
        for (int i = beg + slot; i < end; i += 4) {
            int2 e = csr[i];
            acc += __int_as_float(e.y) * T2[(size_t)e.x * T2S + c];
        }
    }
    acc += __shfl_xor(acc, 16, 64);
    acc += __shfl_xor(acc, 32, 64);
    if (slot == 0 && c < NCLS) {
        float sn = dinv[node];
        sn *= sn;
        out[node * NCLS + c] = acc + sn * T2[(size_t)node * T2S + c] + bias[c];
    }
}

// ================= launch =================

extern "C" void kernel_launch(void* const* d_in, const int* in_sizes, int n_in,
                              void* d_out, int out_size, void* d_ws, size_t ws_size,
                              hipStream_t stream) {
    (void)in_sizes; (void)n_in; (void)out_size; (void)ws_size;
    const float* x       = (const float*)d_in[0];
    const int*   edge    = (const int*)d_in[1];   // [2, NE] int32
    const float* W_stack = (const float*)d_in[2];
    const float* b_stack = (const float*)d_in[3];
    const float* W_out   = (const float*)d_in[4];
    const float* b_out   = (const float*)d_in[5];
    float* out = (float*)d_out;

    char* ws = (char*)d_ws;
    const size_t bigbuf = (size_t)NN * HID * sizeof(float);  // 25.6 MB
    float* X      = (float*)ws;
    float* Y      = (float*)(ws + bigbuf);
    char*  p      = ws + 2 * bigbuf;
    int2*  csr    = (int2*)p;              p += sizeof(int2) * NE;
    float* dinv   = (float*)p;             p += sizeof(float) * NN;
    int*   rowptr = (int*)p;               p += sizeof(int) * (NN + 1);
    int*   counts = (int*)p;               p += sizeof(int) * NN;    // reused as cursor
    int*   bsum   = (int*)p;               p += sizeof(int) * 256;
    p = (char*)(((size_t)p + 15) & ~(size_t)15);
    ushort* Wt4 = (ushort*)p;  p += sizeof(ushort) * 8 * 3 * HID * HID;  // 786 KB
    float* T2b  = (float*)p;   p += sizeof(float) * NN * T2S;            // 3.2 MB

    const int NB_N  = (NN + 255) / 256;
    const int NB_E  = (NE + 255) / 256;
    const int NB_G  = (NN + 127) / 128;        // 391 GEMM tiles (layer 0)
    const int NB_F  = (NN + 63) / 64;          // 782 fused tiles
    const int NB_A  = (NN * 64 + 255) / 256;
    const int NB_SW = (8 * HID * HID + 255) / 256;

    // ---- CSR build (per call) ----
    hipMemsetAsync(counts, 0, sizeof(int) * NN, stream);
    k_count<<<NB_E, 256, 0, stream>>>(edge, counts);
    k_scan1<<<NB_N, 256, 0, stream>>>(counts, rowptr, bsum, dinv);
    k_scan2<<<1, 256, 0, stream>>>(bsum, NB_N);
    k_scan3<<<NB_N, 256, 0, stream>>>(rowptr, bsum);
    k_fill<<<NB_E, 256, 0, stream>>>(edge, rowptr, counts, dinv, csr);

    // ---- one-time weight split ----
    k_split_w<<<NB_SW, 256, 0, stream>>>(W_stack, Wt4);

    // ---- layer 0 GEMM: T_0 = x . W0 ----
    k_mfma_gemm<<<NB_G, 256, 0, stream>>>(x, Wt4, Y);

    // ---- fused layers: gather(l) + GEMM W_{l+1}, l = 0..6 ----
    float* cur = Y;
    float* nxt = X;
    for (int l = 0; l < 7; ++l) {
        k_fused<<<NB_F, 256, 0, stream>>>(cur, Wt4 + (size_t)(l + 1) * 3 * HID * HID,
                                          rowptr, csr, dinv,
                                          b_stack + (size_t)l * HID, nxt);
        float* t = cur; cur = nxt; nxt = t;
    }

    // ---- fused tail: gather(bias 7) + out-proj -> T2 ----
    k_fused_out<<<NB_F, 256, 0, stream>>>(cur, W_out, rowptr, csr, dinv,
                                          b_stack + (size_t)7 * HID, T2b);

    // ---- final sparse layer ----
    k_gather_out<<<NB_A, 256, 0, stream>>>(T2b, out, rowptr, csr, dinv, b_out);
}